// Round 8
// baseline (4099.648 us; speedup 1.0000x reference)
//
#include <hip/hip_runtime.h>

#define T_STEPS 512
#define B_ROWS  64
#define F_DIM   256
#define U_DIM   1024
#define G3      3072   // 3*U
#define LDSK    1292   // 1280 + 12 bf16 pad (bank shift 6/row; measured 0 conflicts)
#define LDS_BYTES (48 * LDSK * 2 + 512)

// h exchange: NSLOT-deep rotation of [4 rowtile groups][64 tiles][512 B data].
// Sentinel protocol: consumers poll the data fragments themselves; tiles are
// re-poisoned with bf16-NaN 3 slots ahead (ordering via each step's vmcnt(0)).
#define NSLOT  5
#define TILE_B 512
#define GRP_B  (64 * TILE_B)      // 32 KB per rowtile group
#define SLOT_B (4 * GRP_B)        // 128 KB per slot
#define SENT   0x7FC17FC1u       // 2x bf16 NaN — h is always finite

typedef __bf16 bf16x8 __attribute__((ext_vector_type(8)));
typedef float  f32x4  __attribute__((ext_vector_type(4)));
typedef unsigned int u32x2 __attribute__((ext_vector_type(2)));
typedef unsigned int u32x4 __attribute__((ext_vector_type(4)));

__device__ __forceinline__ float sigmoidf_(float v) {
    return 1.f / (1.f + __expf(-v));
}
__device__ __forceinline__ float tanhf_(float v) {
    float e2 = __expf(2.f * v);
    return 1.f - 2.f / (e2 + 1.f);
}

// ---------------------------------------------------------------------------
// Transpose + cvt for the recurrent kernel:
// src [1024][3072] f32 -> dst [3072][1024] bf16
// ---------------------------------------------------------------------------
__global__ __launch_bounds__(256) void transpose_cvt_kernel(
    const float* __restrict__ src, __bf16* __restrict__ dst, int Kdim)
{
    __shared__ float tile[32][33];
    const int n0 = blockIdx.x * 32;
    const int k0 = blockIdx.y * 32;
    const int j  = threadIdx.x & 31;
    const int i0 = threadIdx.x >> 5;   // 0..7
#pragma unroll
    for (int s = 0; s < 4; ++s) {
        int i = i0 * 4 + s;
        tile[i][j] = src[(size_t)(k0 + i) * G3 + n0 + j];
    }
    __syncthreads();
#pragma unroll
    for (int s = 0; s < 4; ++s) {
        int i = i0 * 4 + s;
        dst[(size_t)(n0 + i) * Kdim + k0 + j] = (__bf16)tile[j][i];
    }
}

// ---------------------------------------------------------------------------
// Init: hidden f32 -> bf16 tiles in rotation slot 0; slots 1..4 = sentinel.
// Grid 256 x 256. Kernel-boundary release makes this visible device-wide.
// ---------------------------------------------------------------------------
__global__ __launch_bounds__(256) void init_kernel(
    const float* __restrict__ hidden, char* __restrict__ rot)
{
    const int i = blockIdx.x * 256 + threadIdx.x;   // 0..65535
    const int row = i >> 10, u = i & 1023;
    const int rt = row >> 4, rl = row & 15, c = u >> 4, ul = u & 15;
    *(__bf16*)(rot + rt * GRP_B + c * TILE_B + ((rl << 4) + ul) * 2) =
        (__bf16)hidden[i];
    unsigned* s = (unsigned*)(rot + SLOT_B);        // slots 1..4 = 524288 B
    s[2 * i]     = SENT;
    s[2 * i + 1] = SENT;
}

// ---------------------------------------------------------------------------
// Persistent GRU. Grid = 256 blocks x 64 threads (1 wave, 1 block/CU).
// Block bid: coltile c = bid & 63 (16 u's), rowtile rt = bid >> 6 (16 rows).
// Weights (3 gates x 16 u x 1280 k, bf16) live in LDS for all 512 steps;
// X-part staged directly from the f32 kernel (no ws copy).
// h exchange: 5-slot rotation, sentinel-poll on the data (no flags/footers).
// A-frag: lane holds A[row=l&15][k=(l>>4)*8+e];  B-frag: B[k][col=l&15];
// C/D: col=l&15, row=(l>>4)*4+j.  f32 carry stays in registers.
// ---------------------------------------------------------------------------
__global__ __launch_bounds__(64, 1) void gru_persistent(
    const float* __restrict__ x,       // [64][512][256] f32
    const float* __restrict__ hidden,  // [64][1024] f32
    const float* __restrict__ bias,    // [2][3072] f32
    const float* __restrict__ kern,    // [256][3072] f32 (input kernel)
    const __bf16* __restrict__ Rt,     // [3072][1024] bf16
    char* __restrict__ rot,            // NSLOT * SLOT_B bytes
    float* __restrict__ out)           // [64][512][1024] f32 (+ state tail)
{
    extern __shared__ __bf16 wlds[];   // [48][LDSK] weights + 512B pack tile
    __bf16* hpack = wlds + 48 * LDSK;  // [16][16] bf16
    const int lane = threadIdx.x & 63;
    const int rc   = lane & 15;
    const int kg   = lane >> 4;
    const int bid  = blockIdx.x;
    const int c    = bid & 63;
    const int rt   = bid >> 6;
    const int u    = (c << 4) + rc;
    const int row0 = rt << 4;

    // ---- stage weight slice into LDS (once). X-part straight from f32. ----
    for (int i = lane; i < 48 * 160; i += 64) {
        const int rrow = i / 160;
        const int ch   = i - rrow * 160;          // 16B chunk index
        const int g    = rrow >> 4;
        const int ul   = rrow & 15;
        const int gu   = g * U_DIM + (c << 4) + ul;
        if (ch < 32) {
#pragma unroll
            for (int e = 0; e < 8; ++e)
                wlds[rrow * LDSK + ch * 8 + e] =
                    (__bf16)kern[(size_t)(ch * 8 + e) * G3 + gu];
        } else {
            *(bf16x8*)(wlds + rrow * LDSK + ch * 8) =
                *(const bf16x8*)(Rt + (size_t)gu * U_DIM + (ch - 32) * 8);
        }
    }
    __syncthreads();

    // ---- per-thread invariants ----
    float hprev[4];
#pragma unroll
    for (int j = 0; j < 4; ++j)
        hprev[j] = hidden[(size_t)(row0 + (kg << 2) + j) * U_DIM + u];

    const float bz_ = bias[u]             + bias[G3 + u];
    const float br_ = bias[U_DIM + u]     + bias[G3 + U_DIM + u];
    const float bhx = bias[2 * U_DIM + u];
    const float bhr = bias[G3 + 2 * U_DIM + u];

    const __bf16* pz = wlds + (0 * 16 + rc) * LDSK + (kg << 3);
    const __bf16* pr = wlds + (1 * 16 + rc) * LDSK + (kg << 3);
    const __bf16* ph = wlds + (2 * 16 + rc) * LDSK + (kg << 3);

    const float* xbase = x + (size_t)(row0 + rc) * (T_STEPS * F_DIM) + (kg << 3);

    const int grp_b = rt * GRP_B;
    // consumer: byte offset within the group of my k-chunk-0 fragment
    const int lan_b = ((kg >> 1) * TILE_B) + (rc << 5) + ((kg & 1) << 4);
    // producer: my tile's per-lane 8B slot (within a slot buffer)
    const int my_b  = grp_b + c * TILE_B + (lane << 3);

    int slot_r = 0, slot_w = 1, slot_p = 3;
    const u32x2 sentv = { SENT, SENT };

    for (int t = 0; t < T_STEPS; ++t) {
        f32x4 accZ  = {0.f, 0.f, 0.f, 0.f};
        f32x4 accR  = {0.f, 0.f, 0.f, 0.f};
        f32x4 accHX = {0.f, 0.f, 0.f, 0.f};
        f32x4 accHR = {0.f, 0.f, 0.f, 0.f};

        // ---- X phase (independent of h) ----
        const float* ap = xbase + t * F_DIM;
#pragma unroll
        for (int k0 = 0; k0 < F_DIM; k0 += 32) {
            const float4 a0 = *(const float4*)(ap + k0);
            const float4 a1 = *(const float4*)(ap + k0 + 4);
            bf16x8 af;
            af[0] = (__bf16)a0.x; af[1] = (__bf16)a0.y;
            af[2] = (__bf16)a0.z; af[3] = (__bf16)a0.w;
            af[4] = (__bf16)a1.x; af[5] = (__bf16)a1.y;
            af[6] = (__bf16)a1.z; af[7] = (__bf16)a1.w;
            accZ  = __builtin_amdgcn_mfma_f32_16x16x32_bf16(af, *(const bf16x8*)(pz + k0), accZ,  0, 0, 0);
            accR  = __builtin_amdgcn_mfma_f32_16x16x32_bf16(af, *(const bf16x8*)(pr + k0), accR,  0, 0, 0);
            accHX = __builtin_amdgcn_mfma_f32_16x16x32_bf16(af, *(const bf16x8*)(ph + k0), accHX, 0, 0, 0);
        }

        // ---- h(t-1) fragment loads straight to registers (MALL bypass) ----
        const char* hb = rot + slot_r * SLOT_B + grp_b + lan_b;
        bf16x8 hfrag[32];
#define HL(ki, m, lit)                                                         \
        asm volatile("global_load_dwordx4 %0, %1, off offset:" lit " sc0 sc1"  \
                     : "=v"(hfrag[ki]) : "v"(hb + (m) * 4096) : "memory");
#define HLOADS()                                                               \
        HL(0, 0,"0") HL(1, 0,"1024") HL(2, 0,"2048") HL(3, 0,"3072")           \
        HL(4, 1,"0") HL(5, 1,"1024") HL(6, 1,"2048") HL(7, 1,"3072")           \
        HL(8, 2,"0") HL(9, 2,"1024") HL(10,2,"2048") HL(11,2,"3072")           \
        HL(12,3,"0") HL(13,3,"1024") HL(14,3,"2048") HL(15,3,"3072")           \
        HL(16,4,"0") HL(17,4,"1024") HL(18,4,"2048") HL(19,4,"3072")           \
        HL(20,5,"0") HL(21,5,"1024") HL(22,5,"2048") HL(23,5,"3072")           \
        HL(24,6,"0") HL(25,6,"1024") HL(26,6,"2048") HL(27,6,"3072")           \
        HL(28,7,"0") HL(29,7,"1024") HL(30,7,"2048") HL(31,7,"3072")
        HLOADS()

        // ---- sentinel poll: every fragment dword-pair must be real data.
        //      (vmcnt(0) here also drains last step's stores incl. poison.) ----
        for (;;) {
            asm volatile("s_waitcnt vmcnt(0)" ::: "memory");
            __builtin_amdgcn_sched_barrier(0);
            int ok = 1;
#pragma unroll
            for (int ki = 0; ki < 32; ++ki) {
                const u32x4 w = __builtin_bit_cast(u32x4, hfrag[ki]);
                ok &= (w[0] != SENT) & (w[2] != SENT);
            }
            if (__all(ok)) break;
            HLOADS()
        }
#undef HLOADS
#undef HL

        // ---- H phase: K=1024, A from registers, B from LDS (k offset 256) ----
#pragma unroll
        for (int ki = 0; ki < 32; ++ki) {
            const bf16x8 af = hfrag[ki];
            accZ  = __builtin_amdgcn_mfma_f32_16x16x32_bf16(af, *(const bf16x8*)(pz + F_DIM + ki * 32), accZ,  0, 0, 0);
            accR  = __builtin_amdgcn_mfma_f32_16x16x32_bf16(af, *(const bf16x8*)(pr + F_DIM + ki * 32), accR,  0, 0, 0);
            accHR = __builtin_amdgcn_mfma_f32_16x16x32_bf16(af, *(const bf16x8*)(ph + F_DIM + ki * 32), accHR, 0, 0, 0);
        }

        // ---- gates in f32, register carry ----
        float hn[4];
#pragma unroll
        for (int j = 0; j < 4; ++j) {
            const float z  = sigmoidf_(accZ[j] + bz_);
            const float r  = sigmoidf_(accR[j] + br_);
            const float hh = tanhf_(accHX[j] + bhx + r * (accHR[j] + bhr));
            hn[j] = z * hprev[j] + (1.f - z) * hh;
            hprev[j] = hn[j];
        }

        // ---- publish: pack via LDS (single wave), ONE 8B data store/lane ----
#pragma unroll
        for (int j = 0; j < 4; ++j)
            hpack[(((kg << 2) + j) << 4) + rc] = (__bf16)hn[j];
        const u32x2 hv = *(const u32x2*)(hpack + ((lane >> 2) << 4) + ((lane & 3) << 2));
        asm volatile("global_store_dwordx2 %0, %1, off sc0 sc1"
                     :: "v"(rot + slot_w * SLOT_B + my_b), "v"(hv) : "memory");

        // ---- out stores (off the critical path) ----
#pragma unroll
        for (int j = 0; j < 4; ++j) {
            const int row = row0 + (kg << 2) + j;
            out[((size_t)row * T_STEPS + t) * U_DIM + u] = hn[j];
            if (t == T_STEPS - 1)
                out[(size_t)B_ROWS * T_STEPS * U_DIM + (size_t)row * U_DIM + u] = hn[j];
        }

        // ---- re-poison my tile 3 slots ahead (drained by next poll) ----
        asm volatile("global_store_dwordx2 %0, %1, off sc0 sc1"
                     :: "v"(rot + slot_p * SLOT_B + my_b), "v"(sentv) : "memory");

        if (++slot_r == NSLOT) slot_r = 0;
        if (++slot_w == NSLOT) slot_w = 0;
        if (++slot_p == NSLOT) slot_p = 0;
    }
}

extern "C" void kernel_launch(void* const* d_in, const int* in_sizes, int n_in,
                              void* d_out, int out_size, void* d_ws, size_t ws_size,
                              hipStream_t stream)
{
    const float* x      = (const float*)d_in[0];  // [64,512,256]
    const float* hidden = (const float*)d_in[1];  // [64,1024]
    const float* kernel = (const float*)d_in[2];  // [256,3072]
    const float* rker   = (const float*)d_in[3];  // [1024,3072]
    const float* bias   = (const float*)d_in[4];  // [2,3072]
    float* out = (float*)d_out;

    const size_t rt_el = (size_t)G3 * U_DIM;
    __bf16* Rt = (__bf16*)d_ws;                   // 6.29 MB
    char* rot  = (char*)(Rt + rt_el);             // 640 KB (5 slots)

    hipLaunchKernelGGL(transpose_cvt_kernel, dim3(G3 / 32, U_DIM / 32), dim3(256),
                       0, stream, rker, Rt, U_DIM);
    hipLaunchKernelGGL(init_kernel, dim3(256), dim3(256), 0, stream, hidden, rot);

    void* kx = (void*)&x;  void* kh = (void*)&hidden; void* kb = (void*)&bias;
    void* kk = (void*)&kernel; void* kR = (void*)&Rt;
    void* kr = (void*)&rot; void* ko = (void*)&out;
    void* args[7] = { kx, kh, kb, kk, kR, kr, ko };

    auto kfn = gru_persistent;
    (void)hipFuncSetAttribute((const void*)kfn,
                              hipFuncAttributeMaxDynamicSharedMemorySize, LDS_BYTES);
    hipError_t ce = hipLaunchCooperativeKernel(kfn, dim3(256), dim3(64), args,
                                               LDS_BYTES, stream);
    if (ce != hipSuccess) {
        // Fallback: plain launch. At 1 block/CU (124.5 KB LDS, 64 threads) all
        // 256 blocks are co-resident on the 256-CU device, so the spin
        // protocol remains deadlock-free.
        hipLaunchKernelGGL(gru_persistent, dim3(256), dim3(64), LDS_BYTES, stream,
                           x, hidden, bias, kernel, Rt, rot, out);
    }
}

// Round 9
// 3597.679 us; speedup vs baseline: 1.1395x; 1.1395x over previous
//
#include <hip/hip_runtime.h>

#define T_STEPS 512
#define B_ROWS  64
#define F_DIM   256
#define U_DIM   1024
#define G3      3072   // 3*U
#define LDSK    1292   // 1280 + 12 bf16 pad
#define W_BYTES (48 * LDSK * 2)           // 124032
#define PACC_BYTES (2 * 12 * 64 * 16)     // parity x (4acc x 3waves) x 64 lanes x 16B = 24576
#define LDS_BYTES (W_BYTES + PACC_BYTES + 512)

// h exchange: [4 rowtile groups][64 tiles of 512 B], double-buffered + flags.
#define TILE_B 512
#define GRP_B  (64 * TILE_B)      // 32 KB per rowtile group
#define HBUF_B (4 * GRP_B)        // 128 KB per buffer

typedef __bf16 bf16x8 __attribute__((ext_vector_type(8)));
typedef float  f32x4  __attribute__((ext_vector_type(4)));
typedef unsigned int u32x2 __attribute__((ext_vector_type(2)));

__device__ __forceinline__ float sigmoidf_(float v) {
    return 1.f / (1.f + __expf(-v));
}
__device__ __forceinline__ float tanhf_(float v) {
    float e2 = __expf(2.f * v);
    return 1.f - 2.f / (e2 + 1.f);
}

// ---------------------------------------------------------------------------
// Transpose + cvt recurrent kernel: [1024][3072] f32 -> [3072][1024] bf16
// ---------------------------------------------------------------------------
__global__ __launch_bounds__(256) void transpose_cvt_kernel(
    const float* __restrict__ src, __bf16* __restrict__ dst, int Kdim)
{
    __shared__ float tile[32][33];
    const int n0 = blockIdx.x * 32;
    const int k0 = blockIdx.y * 32;
    const int j  = threadIdx.x & 31;
    const int i0 = threadIdx.x >> 5;
#pragma unroll
    for (int s = 0; s < 4; ++s) {
        int i = i0 * 4 + s;
        tile[i][j] = src[(size_t)(k0 + i) * G3 + n0 + j];
    }
    __syncthreads();
#pragma unroll
    for (int s = 0; s < 4; ++s) {
        int i = i0 * 4 + s;
        dst[(size_t)(n0 + i) * Kdim + k0 + j] = (__bf16)tile[j][i];
    }
}

// ---------------------------------------------------------------------------
// Init: hidden f32 -> bf16 tiles in hbufA; zero flags. Grid 256 x 256.
// ---------------------------------------------------------------------------
__global__ __launch_bounds__(256) void init_kernel(
    const float* __restrict__ hidden, char* __restrict__ hbufA,
    unsigned int* __restrict__ flags)
{
    const int i = blockIdx.x * 256 + threadIdx.x;   // 0..65535
    const int row = i >> 10, u = i & 1023;
    const int rt = row >> 4, rl = row & 15, c = u >> 4, ul = u & 15;
    *(__bf16*)(hbufA + rt * GRP_B + c * TILE_B + ((rl << 4) + ul) * 2) =
        (__bf16)hidden[i];
    if (blockIdx.x == 0) flags[threadIdx.x] = 0u;
}

// ---------------------------------------------------------------------------
// Persistent GRU. Grid = 256 blocks x 256 threads (4 waves, 1 block/CU).
// Block bid: coltile c = bid & 63 (16 u's), rowtile rt = bid >> 6 (16 rows).
// K-SPLIT: wave w owns H k-slice [256w,256w+256) (8 frags, 24 MFMAs) and
// X k-slice [64w,64w+64). Waves 1-3 write partial accs to LDS (parity
// double-buffered); one __syncthreads(); wave 0 reduces + gates + publishes
// (r3 drain+flag protocol, 512B packed tiles, early flag probe).
// A-frag: lane holds A[row=l&15][k=(l>>4)*8+e];  B-frag: B[k][col=l&15];
// C/D: col=l&15, row=(l>>4)*4+j.  f32 carry in wave-0 registers.
// ---------------------------------------------------------------------------
__global__ __launch_bounds__(256, 1) void gru_persistent(
    const float* __restrict__ x,       // [64][512][256] f32
    const float* __restrict__ hidden,  // [64][1024] f32
    const float* __restrict__ bias,    // [2][3072] f32
    const float* __restrict__ kern,    // [256][3072] f32 (input kernel)
    const __bf16* __restrict__ Rt,     // [3072][1024] bf16
    char* __restrict__ hbufA,          // HBUF_B bytes, tiled
    char* __restrict__ hbufB,
    unsigned int* __restrict__ flags,  // [256]
    float* __restrict__ out)           // [64][512][1024] f32 (+ state tail)
{
    extern __shared__ char lds_raw[];
    __bf16* wlds  = (__bf16*)lds_raw;               // [48][LDSK]
    float*  pacc  = (float*)(lds_raw + W_BYTES);    // partial accs
    __bf16* hpack = (__bf16*)(lds_raw + W_BYTES + PACC_BYTES); // [16][16]

    const int tid  = threadIdx.x;
    const int lane = tid & 63;
    const int wv   = tid >> 6;        // 0..3
    const int rc   = lane & 15;
    const int kg   = lane >> 4;
    const int bid  = blockIdx.x;
    const int c    = bid & 63;
    const int rt   = bid >> 6;
    const int u    = (c << 4) + rc;
    const int row0 = rt << 4;

    if (wv == 0) __builtin_amdgcn_s_setprio(1);   // wave 0 is the critical wave

    // ---- stage weight slice into LDS (once). X-part straight from f32. ----
    for (int i = tid; i < 48 * 160; i += 256) {
        const int rrow = i / 160;
        const int ch   = i - rrow * 160;          // 16B chunk index
        const int g    = rrow >> 4;
        const int ul   = rrow & 15;
        const int gu   = g * U_DIM + (c << 4) + ul;
        if (ch < 32) {
#pragma unroll
            for (int e = 0; e < 8; ++e)
                wlds[rrow * LDSK + ch * 8 + e] =
                    (__bf16)kern[(size_t)(ch * 8 + e) * G3 + gu];
        } else {
            *(bf16x8*)(wlds + rrow * LDSK + ch * 8) =
                *(const bf16x8*)(Rt + (size_t)gu * U_DIM + (ch - 32) * 8);
        }
    }
    __syncthreads();

    // ---- per-thread invariants ----
    float hprev[4];
#pragma unroll
    for (int j = 0; j < 4; ++j)
        hprev[j] = hidden[(size_t)(row0 + (kg << 2) + j) * U_DIM + u];

    const float bz_ = bias[u]             + bias[G3 + u];
    const float br_ = bias[U_DIM + u]     + bias[G3 + U_DIM + u];
    const float bhx = bias[2 * U_DIM + u];
    const float bhr = bias[G3 + 2 * U_DIM + u];

    const __bf16* pz = wlds + (0 * 16 + rc) * LDSK + (kg << 3);
    const __bf16* pr = wlds + (1 * 16 + rc) * LDSK + (kg << 3);
    const __bf16* ph = wlds + (2 * 16 + rc) * LDSK + (kg << 3);
    const int xk0 = wv << 6;                       // X k-slice base
    const int hk0 = F_DIM + (wv << 8);             // H weight k base in LDS rows

    const float* xbase = x + (size_t)(row0 + rc) * (T_STEPS * F_DIM)
                           + xk0 + (kg << 3);

    const int grp_b = rt * GRP_B;
    // consumer: my wave's fragment base within the group
    const int lan_b = (wv << 13) + ((kg >> 1) << 9) + (rc << 5) + ((kg & 1) << 4);
    // producer (wave 0): my tile's per-lane 8B slot
    const int my_b  = grp_b + c * TILE_B + (lane << 3);

    const unsigned int* fpw = flags + (rt << 6) + (wv << 4) + (lane & 15);

    for (int t = 0; t < T_STEPS; ++t) {
        f32x4 accZ  = {0.f, 0.f, 0.f, 0.f};
        f32x4 accR  = {0.f, 0.f, 0.f, 0.f};
        f32x4 accHX = {0.f, 0.f, 0.f, 0.f};
        f32x4 accHR = {0.f, 0.f, 0.f, 0.f};

        const char* hread  = (t & 1) ? hbufB : hbufA;
        char*       hwrite = (t & 1) ? hbufA : hbufB;
        const int   p      = t & 1;

        // ---- early flag probe (this wave's 16 producers) ----
        unsigned f0 = 0u;
        if (t > 0) {
            asm volatile("global_load_dword %0, %1, off sc0 sc1"
                         : "=v"(f0) : "v"(fpw) : "memory");
        }

        // ---- X phase: my 64-k slice (2 chunks of 32) ----
        const float* ap = xbase + t * F_DIM;
#pragma unroll
        for (int k0 = 0; k0 < 64; k0 += 32) {
            const float4 a0 = *(const float4*)(ap + k0);
            const float4 a1 = *(const float4*)(ap + k0 + 4);
            bf16x8 af;
            af[0] = (__bf16)a0.x; af[1] = (__bf16)a0.y;
            af[2] = (__bf16)a0.z; af[3] = (__bf16)a0.w;
            af[4] = (__bf16)a1.x; af[5] = (__bf16)a1.y;
            af[6] = (__bf16)a1.z; af[7] = (__bf16)a1.w;
            accZ  = __builtin_amdgcn_mfma_f32_16x16x32_bf16(af, *(const bf16x8*)(pz + xk0 + k0), accZ,  0, 0, 0);
            accR  = __builtin_amdgcn_mfma_f32_16x16x32_bf16(af, *(const bf16x8*)(pr + xk0 + k0), accR,  0, 0, 0);
            accHX = __builtin_amdgcn_mfma_f32_16x16x32_bf16(af, *(const bf16x8*)(ph + xk0 + k0), accHX, 0, 0, 0);
        }

        // ---- flag wait: my 16 producers must have published h(t-1) ----
        if (t > 0) {
            asm volatile("s_waitcnt vmcnt(0)" : "+v"(f0) :: "memory");
            __builtin_amdgcn_sched_barrier(0);
            while (!__all((int)(f0 >= (unsigned)t))) {
                asm volatile("global_load_dword %0, %1, off sc0 sc1\n\t"
                             "s_waitcnt vmcnt(0)"
                             : "=v"(f0) : "v"(fpw) : "memory");
            }
        }

        // ---- my 8 h(t-1) fragments straight to registers ----
        const char* hb = hread + grp_b + lan_b;
        bf16x8 hfrag[8];
#define HL(ki, m, lit)                                                         \
        asm volatile("global_load_dwordx4 %0, %1, off offset:" lit " sc0 sc1"  \
                     : "=v"(hfrag[ki]) : "v"(hb + (m) * 4096) : "memory");
        HL(0,0,"0") HL(1,0,"1024") HL(2,0,"2048") HL(3,0,"3072")
        HL(4,1,"0") HL(5,1,"1024") HL(6,1,"2048") HL(7,1,"3072")
#undef HL

        // ---- H phase: first half overlapped with remaining load flight ----
        asm volatile("s_waitcnt vmcnt(4)" ::: "memory");
        __builtin_amdgcn_sched_barrier(0);
#pragma unroll
        for (int ki = 0; ki < 4; ++ki) {
            const bf16x8 af = hfrag[ki];
            accZ  = __builtin_amdgcn_mfma_f32_16x16x32_bf16(af, *(const bf16x8*)(pz + hk0 + ki * 32), accZ,  0, 0, 0);
            accR  = __builtin_amdgcn_mfma_f32_16x16x32_bf16(af, *(const bf16x8*)(pr + hk0 + ki * 32), accR,  0, 0, 0);
            accHR = __builtin_amdgcn_mfma_f32_16x16x32_bf16(af, *(const bf16x8*)(ph + hk0 + ki * 32), accHR, 0, 0, 0);
        }
        asm volatile("s_waitcnt vmcnt(0)" ::: "memory");
        __builtin_amdgcn_sched_barrier(0);
#pragma unroll
        for (int ki = 4; ki < 8; ++ki) {
            const bf16x8 af = hfrag[ki];
            accZ  = __builtin_amdgcn_mfma_f32_16x16x32_bf16(af, *(const bf16x8*)(pz + hk0 + ki * 32), accZ,  0, 0, 0);
            accR  = __builtin_amdgcn_mfma_f32_16x16x32_bf16(af, *(const bf16x8*)(pr + hk0 + ki * 32), accR,  0, 0, 0);
            accHR = __builtin_amdgcn_mfma_f32_16x16x32_bf16(af, *(const bf16x8*)(ph + hk0 + ki * 32), accHR, 0, 0, 0);
        }

        // ---- waves 1-3: dump partials (parity-buffered, 16B/lane) ----
        if (wv != 0) {
            const int w1 = wv - 1;
            *(f32x4*)&pacc[(((p * 12) + 0 * 3 + w1) * 64 + lane) * 4] = accZ;
            *(f32x4*)&pacc[(((p * 12) + 1 * 3 + w1) * 64 + lane) * 4] = accR;
            *(f32x4*)&pacc[(((p * 12) + 2 * 3 + w1) * 64 + lane) * 4] = accHX;
            *(f32x4*)&pacc[(((p * 12) + 3 * 3 + w1) * 64 + lane) * 4] = accHR;
        }
        __syncthreads();

        // ---- wave 0: reduce, gates, publish, flag, out ----
        if (wv == 0) {
#pragma unroll
            for (int w1 = 0; w1 < 3; ++w1) {
                accZ  += *(const f32x4*)&pacc[(((p * 12) + 0 * 3 + w1) * 64 + lane) * 4];
                accR  += *(const f32x4*)&pacc[(((p * 12) + 1 * 3 + w1) * 64 + lane) * 4];
                accHX += *(const f32x4*)&pacc[(((p * 12) + 2 * 3 + w1) * 64 + lane) * 4];
                accHR += *(const f32x4*)&pacc[(((p * 12) + 3 * 3 + w1) * 64 + lane) * 4];
            }
            float hn[4];
#pragma unroll
            for (int j = 0; j < 4; ++j) {
                const float z  = sigmoidf_(accZ[j] + bz_);
                const float r  = sigmoidf_(accR[j] + br_);
                const float hh = tanhf_(accHX[j] + bhx + r * (accHR[j] + bhr));
                hn[j] = z * hprev[j] + (1.f - z) * hh;
                hprev[j] = hn[j];
            }
            // pack tile via LDS (single wave), one coalesced 8B store/lane
#pragma unroll
            for (int j = 0; j < 4; ++j)
                hpack[(((kg << 2) + j) << 4) + rc] = (__bf16)hn[j];
            const u32x2 hv = *(const u32x2*)(hpack + ((lane >> 2) << 4) + ((lane & 3) << 2));
            asm volatile("global_store_dwordx2 %0, %1, off sc0 sc1"
                         :: "v"(hwrite + my_b), "v"(hv) : "memory");
            asm volatile("s_waitcnt vmcnt(0)" ::: "memory");
            if (lane == 0) {
                const unsigned tv = (unsigned)(t + 1);
                asm volatile("global_store_dword %0, %1, off sc0 sc1"
                             :: "v"(flags + bid), "v"(tv) : "memory");
            }
            // out stores AFTER the publish (off the critical path)
#pragma unroll
            for (int j = 0; j < 4; ++j) {
                const int row = row0 + (kg << 2) + j;
                out[((size_t)row * T_STEPS + t) * U_DIM + u] = hn[j];
                if (t == T_STEPS - 1)
                    out[(size_t)B_ROWS * T_STEPS * U_DIM + (size_t)row * U_DIM + u] = hn[j];
            }
        }
    }
}

extern "C" void kernel_launch(void* const* d_in, const int* in_sizes, int n_in,
                              void* d_out, int out_size, void* d_ws, size_t ws_size,
                              hipStream_t stream)
{
    const float* x      = (const float*)d_in[0];  // [64,512,256]
    const float* hidden = (const float*)d_in[1];  // [64,1024]
    const float* kernel = (const float*)d_in[2];  // [256,3072]
    const float* rker   = (const float*)d_in[3];  // [1024,3072]
    const float* bias   = (const float*)d_in[4];  // [2,3072]
    float* out = (float*)d_out;

    const size_t rt_el = (size_t)G3 * U_DIM;
    __bf16* Rt = (__bf16*)d_ws;                   // 6.29 MB
    char* hA = (char*)(Rt + rt_el);               // 128 KB
    char* hB = hA + HBUF_B;                       // 128 KB
    unsigned int* flags = (unsigned int*)(hB + HBUF_B);

    hipLaunchKernelGGL(transpose_cvt_kernel, dim3(G3 / 32, U_DIM / 32), dim3(256),
                       0, stream, rker, Rt, U_DIM);
    hipLaunchKernelGGL(init_kernel, dim3(256), dim3(256), 0, stream,
                       hidden, hA, flags);

    void* kx = (void*)&x;  void* kh = (void*)&hidden; void* kb = (void*)&bias;
    void* kk = (void*)&kernel; void* kR = (void*)&Rt;
    void* kA = (void*)&hA; void* kB2 = (void*)&hB;
    void* kF = (void*)&flags; void* ko = (void*)&out;
    void* args[9] = { kx, kh, kb, kk, kR, kA, kB2, kF, ko };

    auto kfn = gru_persistent;
    (void)hipFuncSetAttribute((const void*)kfn,
                              hipFuncAttributeMaxDynamicSharedMemorySize, LDS_BYTES);
    hipError_t ce = hipLaunchCooperativeKernel(kfn, dim3(256), dim3(256), args,
                                               LDS_BYTES, stream);
    if (ce != hipSuccess) {
        // Fallback: plain launch. 1 block/CU (149 KB LDS) on 256 CUs -> all
        // blocks co-resident; the spin protocol remains deadlock-free.
        hipLaunchKernelGGL(gru_persistent, dim3(256), dim3(256), LDS_BYTES, stream,
                           x, hidden, bias, kernel, Rt, hA, hB, flags, out);
    }
}

// Round 10
// 2272.975 us; speedup vs baseline: 1.8036x; 1.5828x over previous
//
#include <hip/hip_runtime.h>

#define T_STEPS 512
#define B_ROWS  64
#define F_DIM   256
#define U_DIM   1024
#define G3      3072   // 3*U
#define LDSK    1292   // 1280 + 12 bf16 pad
#define W_BYTES (48 * LDSK * 2)           // 124032
#define PACC_BYTES (2 * 12 * 64 * 16)     // parity x (4acc x 3waves) x 64 lanes x 16B
#define LDS_BYTES (W_BYTES + PACC_BYTES + 512)

// h exchange: 5-slot rotation of [4 rowtile groups][64 tiles][512 B].
// Sentinel protocol (r8, proven): data IS the signal; tiles re-poisoned with
// bf16-NaN 3 slots ahead; ordering via each step's own vmcnt(0) drain.
#define NSLOT  5
#define TILE_B 512
#define GRP_B  (64 * TILE_B)      // 32 KB per rowtile group
#define SLOT_B (4 * GRP_B)        // 128 KB per slot
#define SENT   0x7FC17FC1u        // 2x bf16 NaN — h is always finite

typedef __bf16 bf16x8 __attribute__((ext_vector_type(8)));
typedef float  f32x4  __attribute__((ext_vector_type(4)));
typedef unsigned int u32x2 __attribute__((ext_vector_type(2)));
typedef unsigned int u32x4 __attribute__((ext_vector_type(4)));

__device__ __forceinline__ float sigmoidf_(float v) {
    return 1.f / (1.f + __expf(-v));
}
__device__ __forceinline__ float tanhf_(float v) {
    float e2 = __expf(2.f * v);
    return 1.f - 2.f / (e2 + 1.f);
}

// ---------------------------------------------------------------------------
// Transpose + cvt recurrent kernel: [1024][3072] f32 -> [3072][1024] bf16
// ---------------------------------------------------------------------------
__global__ __launch_bounds__(256) void transpose_cvt_kernel(
    const float* __restrict__ src, __bf16* __restrict__ dst, int Kdim)
{
    __shared__ float tile[32][33];
    const int n0 = blockIdx.x * 32;
    const int k0 = blockIdx.y * 32;
    const int j  = threadIdx.x & 31;
    const int i0 = threadIdx.x >> 5;
#pragma unroll
    for (int s = 0; s < 4; ++s) {
        int i = i0 * 4 + s;
        tile[i][j] = src[(size_t)(k0 + i) * G3 + n0 + j];
    }
    __syncthreads();
#pragma unroll
    for (int s = 0; s < 4; ++s) {
        int i = i0 * 4 + s;
        dst[(size_t)(n0 + i) * Kdim + k0 + j] = (__bf16)tile[j][i];
    }
}

// ---------------------------------------------------------------------------
// Init: hidden f32 -> bf16 tiles in slot 0; slots 1..4 = sentinel.
// ---------------------------------------------------------------------------
__global__ __launch_bounds__(256) void init_kernel(
    const float* __restrict__ hidden, char* __restrict__ rot)
{
    const int i = blockIdx.x * 256 + threadIdx.x;   // 0..65535
    const int row = i >> 10, u = i & 1023;
    const int rt = row >> 4, rl = row & 15, c = u >> 4, ul = u & 15;
    *(__bf16*)(rot + rt * GRP_B + c * TILE_B + ((rl << 4) + ul) * 2) =
        (__bf16)hidden[i];
    unsigned* s = (unsigned*)(rot + SLOT_B);        // slots 1..4
    s[2 * i]     = SENT;
    s[2 * i + 1] = SENT;
}

// ---------------------------------------------------------------------------
// Persistent GRU. Grid = 256 blocks x 256 threads (4 waves, 1 block/CU).
// Block (rt = bid>>6: 16 rows, c = bid&63: 16 u's). K-SPLIT: wave w owns
// H k-slice [256w,256w+256) (8 frags) and X k-slice [64w,64w+64).
// Per step, per wave: spec-issue 8 h-loads (slot t%5) -> X-GEMM (covers RTT)
// -> wave0 stores out[t-1] (gap fill) -> sentinel poll own 8 tiles -> H-GEMM
// -> dump partials (waves 1-3, parity LDS) -> sync -> wave0: reduce + gates +
// pack + ONE 8B publish store/lane + poison (t+3)%5. Nothing after publish.
// ---------------------------------------------------------------------------
__global__ __launch_bounds__(256, 1) void gru_persistent(
    const float* __restrict__ x,       // [64][512][256] f32
    const float* __restrict__ hidden,  // [64][1024] f32
    const float* __restrict__ bias,    // [2][3072] f32
    const float* __restrict__ kern,    // [256][3072] f32 (input kernel)
    const __bf16* __restrict__ Rt,     // [3072][1024] bf16
    char* __restrict__ rot,            // NSLOT * SLOT_B bytes
    float* __restrict__ out)           // [64][512][1024] f32 (+ state tail)
{
    extern __shared__ char lds_raw[];
    __bf16* wlds  = (__bf16*)lds_raw;               // [48][LDSK]
    float*  pacc  = (float*)(lds_raw + W_BYTES);
    __bf16* hpack = (__bf16*)(lds_raw + W_BYTES + PACC_BYTES); // [16][16]

    const int tid  = threadIdx.x;
    const int lane = tid & 63;
    const int wv   = tid >> 6;        // 0..3
    const int rc   = lane & 15;
    const int kg   = lane >> 4;
    const int bid  = blockIdx.x;
    const int c    = bid & 63;
    const int rt   = bid >> 6;
    const int u    = (c << 4) + rc;
    const int row0 = rt << 4;

    if (wv == 0) __builtin_amdgcn_s_setprio(1);

    // ---- stage weight slice into LDS (once). X-part straight from f32. ----
    for (int i = tid; i < 48 * 160; i += 256) {
        const int rrow = i / 160;
        const int ch   = i - rrow * 160;
        const int g    = rrow >> 4;
        const int ul   = rrow & 15;
        const int gu   = g * U_DIM + (c << 4) + ul;
        if (ch < 32) {
#pragma unroll
            for (int e = 0; e < 8; ++e)
                wlds[rrow * LDSK + ch * 8 + e] =
                    (__bf16)kern[(size_t)(ch * 8 + e) * G3 + gu];
        } else {
            *(bf16x8*)(wlds + rrow * LDSK + ch * 8) =
                *(const bf16x8*)(Rt + (size_t)gu * U_DIM + (ch - 32) * 8);
        }
    }
    __syncthreads();

    // ---- per-thread invariants ----
    float hprev[4];
#pragma unroll
    for (int j = 0; j < 4; ++j)
        hprev[j] = hidden[(size_t)(row0 + (kg << 2) + j) * U_DIM + u];

    const float bz_ = bias[u]             + bias[G3 + u];
    const float br_ = bias[U_DIM + u]     + bias[G3 + U_DIM + u];
    const float bhx = bias[2 * U_DIM + u];
    const float bhr = bias[G3 + 2 * U_DIM + u];

    const __bf16* pz = wlds + (0 * 16 + rc) * LDSK + (kg << 3);
    const __bf16* pr = wlds + (1 * 16 + rc) * LDSK + (kg << 3);
    const __bf16* ph = wlds + (2 * 16 + rc) * LDSK + (kg << 3);
    const int xk0 = wv << 6;                       // X k-slice base
    const int hk0 = F_DIM + (wv << 8);             // H weight k base

    const float* xbase = x + (size_t)(row0 + rc) * (T_STEPS * F_DIM)
                           + xk0 + (kg << 3);

    const int grp_b = rt * GRP_B;
    // consumer: this wave's fragment base within the group
    const int lan_b = (wv << 13) + ((kg >> 1) << 9) + (rc << 5) + ((kg & 1) << 4);
    // producer (wave 0): my tile's per-lane 8B slot
    const int my_b  = grp_b + c * TILE_B + (lane << 3);

    int slot_r = 0, slot_w = 1, slot_p = 3;
    const u32x2 sentv = { SENT, SENT };

    for (int t = 0; t < T_STEPS; ++t) {
        f32x4 accZ  = {0.f, 0.f, 0.f, 0.f};
        f32x4 accR  = {0.f, 0.f, 0.f, 0.f};
        f32x4 accHX = {0.f, 0.f, 0.f, 0.f};
        f32x4 accHR = {0.f, 0.f, 0.f, 0.f};
        const int p = t & 1;

        // ---- spec-issue my 8 h(t-1) fragment loads (slot t%5) ----
        const char* hb = rot + slot_r * SLOT_B + grp_b + lan_b;
        bf16x8 hfrag[8];
#define HL(ki, m, lit)                                                         \
        asm volatile("global_load_dwordx4 %0, %1, off offset:" lit " sc0 sc1"  \
                     : "=v"(hfrag[ki]) : "v"(hb + (m) * 4096) : "memory");
#define HLOADS()                                                               \
        HL(0,0,"0") HL(1,0,"1024") HL(2,0,"2048") HL(3,0,"3072")               \
        HL(4,1,"0") HL(5,1,"1024") HL(6,1,"2048") HL(7,1,"3072")
        HLOADS()

        // ---- X phase: my 64-k slice (covers the h-load flight) ----
        const float* ap = xbase + t * F_DIM;
#pragma unroll
        for (int k0 = 0; k0 < 64; k0 += 32) {
            const float4 a0 = *(const float4*)(ap + k0);
            const float4 a1 = *(const float4*)(ap + k0 + 4);
            bf16x8 af;
            af[0] = (__bf16)a0.x; af[1] = (__bf16)a0.y;
            af[2] = (__bf16)a0.z; af[3] = (__bf16)a0.w;
            af[4] = (__bf16)a1.x; af[5] = (__bf16)a1.y;
            af[6] = (__bf16)a1.z; af[7] = (__bf16)a1.w;
            accZ  = __builtin_amdgcn_mfma_f32_16x16x32_bf16(af, *(const bf16x8*)(pz + xk0 + k0), accZ,  0, 0, 0);
            accR  = __builtin_amdgcn_mfma_f32_16x16x32_bf16(af, *(const bf16x8*)(pr + xk0 + k0), accR,  0, 0, 0);
            accHX = __builtin_amdgcn_mfma_f32_16x16x32_bf16(af, *(const bf16x8*)(ph + xk0 + k0), accHX, 0, 0, 0);
        }

        // ---- wave0: store out[t-1] here (fills the remaining RTT; these
        //      cached stores ack at L2 and drain cheaply at the poll) ----
        if (wv == 0 && t > 0) {
#pragma unroll
            for (int j = 0; j < 4; ++j) {
                const int row = row0 + (kg << 2) + j;
                out[((size_t)row * T_STEPS + (t - 1)) * U_DIM + u] = hprev[j];
            }
        }

        // ---- sentinel poll: my 8 fragments must be real data ----
        for (;;) {
            asm volatile("s_waitcnt vmcnt(0)" ::: "memory");
            __builtin_amdgcn_sched_barrier(0);
            int ok = 1;
#pragma unroll
            for (int ki = 0; ki < 8; ++ki) {
                const u32x4 w = __builtin_bit_cast(u32x4, hfrag[ki]);
                ok &= (w[0] != SENT) & (w[2] != SENT);
            }
            if (__all(ok)) break;
            HLOADS()
        }
#undef HLOADS
#undef HL

        // ---- H phase: my 256-k slice (8 frags x 3 MFMAs) ----
#pragma unroll
        for (int ki = 0; ki < 8; ++ki) {
            const bf16x8 af = hfrag[ki];
            accZ  = __builtin_amdgcn_mfma_f32_16x16x32_bf16(af, *(const bf16x8*)(pz + hk0 + ki * 32), accZ,  0, 0, 0);
            accR  = __builtin_amdgcn_mfma_f32_16x16x32_bf16(af, *(const bf16x8*)(pr + hk0 + ki * 32), accR,  0, 0, 0);
            accHR = __builtin_amdgcn_mfma_f32_16x16x32_bf16(af, *(const bf16x8*)(ph + hk0 + ki * 32), accHR, 0, 0, 0);
        }

        // ---- waves 1-3: dump partials (parity-buffered) ----
        if (wv != 0) {
            const int w1 = wv - 1;
            *(f32x4*)&pacc[(((p * 12) + 0 * 3 + w1) * 64 + lane) * 4] = accZ;
            *(f32x4*)&pacc[(((p * 12) + 1 * 3 + w1) * 64 + lane) * 4] = accR;
            *(f32x4*)&pacc[(((p * 12) + 2 * 3 + w1) * 64 + lane) * 4] = accHX;
            *(f32x4*)&pacc[(((p * 12) + 3 * 3 + w1) * 64 + lane) * 4] = accHR;
        }
        __syncthreads();

        // ---- wave 0: reduce, gates, publish (single 8B store), poison ----
        if (wv == 0) {
#pragma unroll
            for (int w1 = 0; w1 < 3; ++w1) {
                accZ  += *(const f32x4*)&pacc[(((p * 12) + 0 * 3 + w1) * 64 + lane) * 4];
                accR  += *(const f32x4*)&pacc[(((p * 12) + 1 * 3 + w1) * 64 + lane) * 4];
                accHX += *(const f32x4*)&pacc[(((p * 12) + 2 * 3 + w1) * 64 + lane) * 4];
                accHR += *(const f32x4*)&pacc[(((p * 12) + 3 * 3 + w1) * 64 + lane) * 4];
            }
#pragma unroll
            for (int j = 0; j < 4; ++j) {
                const float z  = sigmoidf_(accZ[j] + bz_);
                const float r  = sigmoidf_(accR[j] + br_);
                const float hh = tanhf_(accHX[j] + bhx + r * (accHR[j] + bhr));
                hprev[j] = z * hprev[j] + (1.f - z) * hh;
            }
            // pack via LDS (single wave), ONE coalesced 8B store per lane
#pragma unroll
            for (int j = 0; j < 4; ++j)
                hpack[(((kg << 2) + j) << 4) + rc] = (__bf16)hprev[j];
            const u32x2 hv = *(const u32x2*)(hpack + ((lane >> 2) << 4) + ((lane & 3) << 2));
            asm volatile("global_store_dwordx2 %0, %1, off sc0 sc1"
                         :: "v"(rot + slot_w * SLOT_B + my_b), "v"(hv) : "memory");
            // re-poison my tile 3 slots ahead (drained by my next poll,
            // which happens before I publish h(t+1) — ordering proof in r8)
            asm volatile("global_store_dwordx2 %0, %1, off sc0 sc1"
                         :: "v"(rot + slot_p * SLOT_B + my_b), "v"(sentv) : "memory");
        }

        if (++slot_r == NSLOT) slot_r = 0;
        if (++slot_w == NSLOT) slot_w = 0;
        if (++slot_p == NSLOT) slot_p = 0;
    }

    // ---- final: out[T-1] + state tail (wave 0) ----
    if (wv == 0) {
#pragma unroll
        for (int j = 0; j < 4; ++j) {
            const int row = row0 + (kg << 2) + j;
            out[((size_t)row * T_STEPS + (T_STEPS - 1)) * U_DIM + u] = hprev[j];
            out[(size_t)B_ROWS * T_STEPS * U_DIM + (size_t)row * U_DIM + u] = hprev[j];
        }
    }
}

extern "C" void kernel_launch(void* const* d_in, const int* in_sizes, int n_in,
                              void* d_out, int out_size, void* d_ws, size_t ws_size,
                              hipStream_t stream)
{
    const float* x      = (const float*)d_in[0];  // [64,512,256]
    const float* hidden = (const float*)d_in[1];  // [64,1024]
    const float* kernel = (const float*)d_in[2];  // [256,3072]
    const float* rker   = (const float*)d_in[3];  // [1024,3072]
    const float* bias   = (const float*)d_in[4];  // [2,3072]
    float* out = (float*)d_out;

    const size_t rt_el = (size_t)G3 * U_DIM;
    __bf16* Rt = (__bf16*)d_ws;                   // 6.29 MB
    char* rot  = (char*)(Rt + rt_el);             // 640 KB (5 slots)

    hipLaunchKernelGGL(transpose_cvt_kernel, dim3(G3 / 32, U_DIM / 32), dim3(256),
                       0, stream, rker, Rt, U_DIM);
    hipLaunchKernelGGL(init_kernel, dim3(256), dim3(256), 0, stream, hidden, rot);

    void* kx = (void*)&x;  void* kh = (void*)&hidden; void* kb = (void*)&bias;
    void* kk = (void*)&kernel; void* kR = (void*)&Rt;
    void* kr = (void*)&rot; void* ko = (void*)&out;
    void* args[7] = { kx, kh, kb, kk, kR, kr, ko };

    auto kfn = gru_persistent;
    (void)hipFuncSetAttribute((const void*)kfn,
                              hipFuncAttributeMaxDynamicSharedMemorySize, LDS_BYTES);
    hipError_t ce = hipLaunchCooperativeKernel(kfn, dim3(256), dim3(256), args,
                                               LDS_BYTES, stream);
    if (ce != hipSuccess) {
        // Fallback: plain launch. 1 block/CU on 256 CUs -> all blocks
        // co-resident; the spin protocol remains deadlock-free.
        hipLaunchKernelGGL(gru_persistent, dim3(256), dim3(256), LDS_BYTES, stream,
                           x, hidden, bias, kernel, Rt, rot, out);
    }
}

// Round 11
// 1379.703 us; speedup vs baseline: 2.9714x; 1.6474x over previous
//
#include <hip/hip_runtime.h>

#define T_STEPS 512
#define B_ROWS  64
#define F_DIM   256
#define U_DIM   1024
#define G3      3072   // 3*U
#define PACC_BYTES (2 * 12 * 64 * 16)     // parity x (4acc x 3waves) x 64 lanes x 16B
#define LDS_BYTES (PACC_BYTES + 512)

// h exchange: 5-slot rotation of [4 rowtile groups][64 tiles][512 B].
// Sentinel protocol (r8/r10, proven): data IS the signal; tiles re-poisoned
// with bf16-NaN 3 slots ahead; ordering via each step's own vmcnt(0) drain.
#define NSLOT  5
#define TILE_B 512
#define GRP_B  (64 * TILE_B)      // 32 KB per rowtile group
#define SLOT_B (4 * GRP_B)        // 128 KB per slot
#define SENT   0x7FC17FC1u        // 2x bf16 NaN — h is always finite

typedef __bf16 bf16x8 __attribute__((ext_vector_type(8)));
typedef float  f32x4  __attribute__((ext_vector_type(4)));
typedef unsigned int u32x2 __attribute__((ext_vector_type(2)));
typedef unsigned int u32x4 __attribute__((ext_vector_type(4)));

__device__ __forceinline__ float sigmoidf_(float v) {
    return 1.f / (1.f + __expf(-v));
}
__device__ __forceinline__ float tanhf_(float v) {
    float e2 = __expf(2.f * v);
    return 1.f - 2.f / (e2 + 1.f);
}

// ---------------------------------------------------------------------------
// Transpose + cvt recurrent kernel: [1024][3072] f32 -> [3072][1024] bf16
// ---------------------------------------------------------------------------
__global__ __launch_bounds__(256) void transpose_cvt_kernel(
    const float* __restrict__ src, __bf16* __restrict__ dst, int Kdim)
{
    __shared__ float tile[32][33];
    const int n0 = blockIdx.x * 32;
    const int k0 = blockIdx.y * 32;
    const int j  = threadIdx.x & 31;
    const int i0 = threadIdx.x >> 5;
#pragma unroll
    for (int s = 0; s < 4; ++s) {
        int i = i0 * 4 + s;
        tile[i][j] = src[(size_t)(k0 + i) * G3 + n0 + j];
    }
    __syncthreads();
#pragma unroll
    for (int s = 0; s < 4; ++s) {
        int i = i0 * 4 + s;
        dst[(size_t)(n0 + i) * Kdim + k0 + j] = (__bf16)tile[j][i];
    }
}

// ---------------------------------------------------------------------------
// Init: hidden f32 -> bf16 tiles in slot 0; slots 1..4 = sentinel.
// ---------------------------------------------------------------------------
__global__ __launch_bounds__(256) void init_kernel(
    const float* __restrict__ hidden, char* __restrict__ rot)
{
    const int i = blockIdx.x * 256 + threadIdx.x;   // 0..65535
    const int row = i >> 10, u = i & 1023;
    const int rt = row >> 4, rl = row & 15, c = u >> 4, ul = u & 15;
    *(__bf16*)(rot + rt * GRP_B + c * TILE_B + ((rl << 4) + ul) * 2) =
        (__bf16)hidden[i];
    unsigned* s = (unsigned*)(rot + SLOT_B);        // slots 1..4
    s[2 * i]     = SENT;
    s[2 * i + 1] = SENT;
}

// ---------------------------------------------------------------------------
// Persistent GRU. Grid = 256 blocks x 256 threads (4 waves, 1 block/CU,
// 1 wave/SIMD -> ~450 VGPR budget/wave). Block (rt=bid>>6, c=bid&63).
// K-SPLIT: wave w owns H k-slice [256w,256w+256) and X k-slice [64w,64w+64).
// ALL B-fragments (30 x bf16x8 = 120 VGPR) live in REGISTERS — zero LDS
// reads in the step loop except the partial-acc exchange.
// Per step: spec-issue 8 h-loads (slot t%5) -> X-GEMM (regs) -> wave0 out[t-1]
// -> sentinel poll -> H-GEMM (regs) -> dump partials -> sync -> wave0:
// reduce + gates + pack + ONE 8B publish store/lane + poison (t+3)%5.
// ---------------------------------------------------------------------------
__global__ __launch_bounds__(256, 1) void gru_persistent(
    const float* __restrict__ x,       // [64][512][256] f32
    const float* __restrict__ hidden,  // [64][1024] f32
    const float* __restrict__ bias,    // [2][3072] f32
    const float* __restrict__ kern,    // [256][3072] f32 (input kernel)
    const __bf16* __restrict__ Rt,     // [3072][1024] bf16
    char* __restrict__ rot,            // NSLOT * SLOT_B bytes
    float* __restrict__ out)           // [64][512][1024] f32 (+ state tail)
{
    extern __shared__ char lds_raw[];
    float*  pacc  = (float*)lds_raw;
    __bf16* hpack = (__bf16*)(lds_raw + PACC_BYTES); // [16][16]

    const int tid  = threadIdx.x;
    const int lane = tid & 63;
    const int wv   = tid >> 6;        // 0..3
    const int rc   = lane & 15;
    const int kg   = lane >> 4;
    const int bid  = blockIdx.x;
    const int c    = bid & 63;
    const int rt   = bid >> 6;
    const int u    = (c << 4) + rc;
    const int row0 = rt << 4;

    if (wv == 0) __builtin_amdgcn_s_setprio(1);

    const int gu0 = u;
    const int gu1 = U_DIM + u;
    const int gu2 = 2 * U_DIM + u;
    const int xk0 = wv << 6;          // X k-slice base

    // ---- hoist ALL B-fragments into registers (once) ----
    bf16x8 whz[8], whr[8], whh[8];    // H-weights: contiguous 16B from Rt
#pragma unroll
    for (int ki = 0; ki < 8; ++ki) {
        const int col = (wv << 8) + (ki << 5) + (kg << 3);
        whz[ki] = *(const bf16x8*)(Rt + (size_t)gu0 * U_DIM + col);
        whr[ki] = *(const bf16x8*)(Rt + (size_t)gu1 * U_DIM + col);
        whh[ki] = *(const bf16x8*)(Rt + (size_t)gu2 * U_DIM + col);
    }
    bf16x8 wxz[2], wxr[2], wxh[2];    // X-weights: scattered one-time f32
#pragma unroll
    for (int fx = 0; fx < 2; ++fx) {
#pragma unroll
        for (int e = 0; e < 8; ++e) {
            const int k = xk0 + fx * 32 + (kg << 3) + e;
            wxz[fx][e] = (__bf16)kern[(size_t)k * G3 + gu0];
            wxr[fx][e] = (__bf16)kern[(size_t)k * G3 + gu1];
            wxh[fx][e] = (__bf16)kern[(size_t)k * G3 + gu2];
        }
    }

    // ---- per-thread invariants ----
    float hprev[4];
#pragma unroll
    for (int j = 0; j < 4; ++j)
        hprev[j] = hidden[(size_t)(row0 + (kg << 2) + j) * U_DIM + u];

    const float bz_ = bias[u]             + bias[G3 + u];
    const float br_ = bias[U_DIM + u]     + bias[G3 + U_DIM + u];
    const float bhx = bias[2 * U_DIM + u];
    const float bhr = bias[G3 + 2 * U_DIM + u];

    const float* xbase = x + (size_t)(row0 + rc) * (T_STEPS * F_DIM)
                           + xk0 + (kg << 3);

    const int grp_b = rt * GRP_B;
    const int lan_b = (wv << 13) + ((kg >> 1) << 9) + (rc << 5) + ((kg & 1) << 4);
    const int my_b  = grp_b + c * TILE_B + (lane << 3);

    int slot_r = 0, slot_w = 1, slot_p = 3;
    const u32x2 sentv = { SENT, SENT };

    for (int t = 0; t < T_STEPS; ++t) {
        f32x4 accZ  = {0.f, 0.f, 0.f, 0.f};
        f32x4 accR  = {0.f, 0.f, 0.f, 0.f};
        f32x4 accHX = {0.f, 0.f, 0.f, 0.f};
        f32x4 accHR = {0.f, 0.f, 0.f, 0.f};
        const int p = t & 1;

        // ---- spec-issue my 8 h(t-1) fragment loads (slot t%5) ----
        const char* hb = rot + slot_r * SLOT_B + grp_b + lan_b;
        bf16x8 hfrag[8];
#define HL(ki, m, lit)                                                         \
        asm volatile("global_load_dwordx4 %0, %1, off offset:" lit " sc0 sc1"  \
                     : "=v"(hfrag[ki]) : "v"(hb + (m) * 4096) : "memory");
#define HLOADS()                                                               \
        HL(0,0,"0") HL(1,0,"1024") HL(2,0,"2048") HL(3,0,"3072")               \
        HL(4,1,"0") HL(5,1,"1024") HL(6,1,"2048") HL(7,1,"3072")
        HLOADS()

        // ---- X phase: my 64-k slice, B-frags from registers ----
        const float* ap = xbase + t * F_DIM;
#pragma unroll
        for (int fx = 0; fx < 2; ++fx) {
            const float4 a0 = *(const float4*)(ap + fx * 32);
            const float4 a1 = *(const float4*)(ap + fx * 32 + 4);
            bf16x8 af;
            af[0] = (__bf16)a0.x; af[1] = (__bf16)a0.y;
            af[2] = (__bf16)a0.z; af[3] = (__bf16)a0.w;
            af[4] = (__bf16)a1.x; af[5] = (__bf16)a1.y;
            af[6] = (__bf16)a1.z; af[7] = (__bf16)a1.w;
            accZ  = __builtin_amdgcn_mfma_f32_16x16x32_bf16(af, wxz[fx], accZ,  0, 0, 0);
            accR  = __builtin_amdgcn_mfma_f32_16x16x32_bf16(af, wxr[fx], accR,  0, 0, 0);
            accHX = __builtin_amdgcn_mfma_f32_16x16x32_bf16(af, wxh[fx], accHX, 0, 0, 0);
        }

        // ---- wave0: store out[t-1] (fills remaining RTT) ----
        if (wv == 0 && t > 0) {
#pragma unroll
            for (int j = 0; j < 4; ++j) {
                const int row = row0 + (kg << 2) + j;
                out[((size_t)row * T_STEPS + (t - 1)) * U_DIM + u] = hprev[j];
            }
        }

        // ---- sentinel poll: my 8 fragments must be real data ----
        for (;;) {
            asm volatile("s_waitcnt vmcnt(0)" ::: "memory");
            __builtin_amdgcn_sched_barrier(0);
            int ok = 1;
#pragma unroll
            for (int ki = 0; ki < 8; ++ki) {
                const u32x4 w = __builtin_bit_cast(u32x4, hfrag[ki]);
                ok &= (w[0] != SENT) & (w[2] != SENT);
            }
            if (__all(ok)) break;
            HLOADS()
        }
#undef HLOADS
#undef HL

        // ---- H phase: 24 pure-register MFMAs ----
#pragma unroll
        for (int ki = 0; ki < 8; ++ki) {
            const bf16x8 af = hfrag[ki];
            accZ  = __builtin_amdgcn_mfma_f32_16x16x32_bf16(af, whz[ki], accZ,  0, 0, 0);
            accR  = __builtin_amdgcn_mfma_f32_16x16x32_bf16(af, whr[ki], accR,  0, 0, 0);
            accHR = __builtin_amdgcn_mfma_f32_16x16x32_bf16(af, whh[ki], accHR, 0, 0, 0);
        }

        // ---- waves 1-3: dump partials (parity-buffered) ----
        if (wv != 0) {
            const int w1 = wv - 1;
            *(f32x4*)&pacc[(((p * 12) + 0 * 3 + w1) * 64 + lane) * 4] = accZ;
            *(f32x4*)&pacc[(((p * 12) + 1 * 3 + w1) * 64 + lane) * 4] = accR;
            *(f32x4*)&pacc[(((p * 12) + 2 * 3 + w1) * 64 + lane) * 4] = accHX;
            *(f32x4*)&pacc[(((p * 12) + 3 * 3 + w1) * 64 + lane) * 4] = accHR;
        }
        __syncthreads();

        // ---- wave 0: reduce, gates, publish (single 8B store), poison ----
        if (wv == 0) {
#pragma unroll
            for (int w1 = 0; w1 < 3; ++w1) {
                accZ  += *(const f32x4*)&pacc[(((p * 12) + 0 * 3 + w1) * 64 + lane) * 4];
                accR  += *(const f32x4*)&pacc[(((p * 12) + 1 * 3 + w1) * 64 + lane) * 4];
                accHX += *(const f32x4*)&pacc[(((p * 12) + 2 * 3 + w1) * 64 + lane) * 4];
                accHR += *(const f32x4*)&pacc[(((p * 12) + 3 * 3 + w1) * 64 + lane) * 4];
            }
#pragma unroll
            for (int j = 0; j < 4; ++j) {
                const float z  = sigmoidf_(accZ[j] + bz_);
                const float r  = sigmoidf_(accR[j] + br_);
                const float hh = tanhf_(accHX[j] + bhx + r * (accHR[j] + bhr));
                hprev[j] = z * hprev[j] + (1.f - z) * hh;
            }
#pragma unroll
            for (int j = 0; j < 4; ++j)
                hpack[(((kg << 2) + j) << 4) + rc] = (__bf16)hprev[j];
            const u32x2 hv = *(const u32x2*)(hpack + ((lane >> 2) << 4) + ((lane & 3) << 2));
            asm volatile("global_store_dwordx2 %0, %1, off sc0 sc1"
                         :: "v"(rot + slot_w * SLOT_B + my_b), "v"(hv) : "memory");
            asm volatile("global_store_dwordx2 %0, %1, off sc0 sc1"
                         :: "v"(rot + slot_p * SLOT_B + my_b), "v"(sentv) : "memory");
        }

        if (++slot_r == NSLOT) slot_r = 0;
        if (++slot_w == NSLOT) slot_w = 0;
        if (++slot_p == NSLOT) slot_p = 0;
    }

    // ---- final: out[T-1] + state tail (wave 0) ----
    if (wv == 0) {
#pragma unroll
        for (int j = 0; j < 4; ++j) {
            const int row = row0 + (kg << 2) + j;
            out[((size_t)row * T_STEPS + (T_STEPS - 1)) * U_DIM + u] = hprev[j];
            out[(size_t)B_ROWS * T_STEPS * U_DIM + (size_t)row * U_DIM + u] = hprev[j];
        }
    }
}

extern "C" void kernel_launch(void* const* d_in, const int* in_sizes, int n_in,
                              void* d_out, int out_size, void* d_ws, size_t ws_size,
                              hipStream_t stream)
{
    const float* x      = (const float*)d_in[0];  // [64,512,256]
    const float* hidden = (const float*)d_in[1];  // [64,1024]
    const float* kernel = (const float*)d_in[2];  // [256,3072]
    const float* rker   = (const float*)d_in[3];  // [1024,3072]
    const float* bias   = (const float*)d_in[4];  // [2,3072]
    float* out = (float*)d_out;

    const size_t rt_el = (size_t)G3 * U_DIM;
    __bf16* Rt = (__bf16*)d_ws;                   // 6.29 MB
    char* rot  = (char*)(Rt + rt_el);             // 640 KB (5 slots)

    hipLaunchKernelGGL(transpose_cvt_kernel, dim3(G3 / 32, U_DIM / 32), dim3(256),
                       0, stream, rker, Rt, U_DIM);
    hipLaunchKernelGGL(init_kernel, dim3(256), dim3(256), 0, stream, hidden, rot);

    void* kx = (void*)&x;  void* kh = (void*)&hidden; void* kb = (void*)&bias;
    void* kk = (void*)&kernel; void* kR = (void*)&Rt;
    void* kr = (void*)&rot; void* ko = (void*)&out;
    void* args[7] = { kx, kh, kb, kk, kR, kr, ko };

    auto kfn = gru_persistent;
    (void)hipFuncSetAttribute((const void*)kfn,
                              hipFuncAttributeMaxDynamicSharedMemorySize, LDS_BYTES);
    hipError_t ce = hipLaunchCooperativeKernel(kfn, dim3(256), dim3(256), args,
                                               LDS_BYTES, stream);
    if (ce != hipSuccess) {
        // Fallback: plain launch. 1 block/CU on 256 CUs -> all blocks
        // co-resident; the spin protocol remains deadlock-free.
        hipLaunchKernelGGL(gru_persistent, dim3(256), dim3(256), LDS_BYTES, stream,
                           x, hidden, bias, kernel, Rt, rot, out);
    }
}